// Round 6
// baseline (502.739 us; speedup 1.0000x reference)
//
#include <hip/hip_runtime.h>
#include <hip/hip_fp16.h>

#define N_NODES 65536
#define N_EDGES 1048576
#define BUCKET  64   // padded CSR slots per node (deg ~ Poisson(16); P(>64) ~ 1e-18)
#define HALF_ELEMS (N_NODES * 32)   // __half elements per feature-half table (4 MB)

typedef float vfloat4 __attribute__((ext_vector_type(4)));
typedef unsigned long long ull;

// ---------------- workspace layout (bytes) ----------------
// counts @ 0x000000   (256 KB)
// dinv   @ 0x040000   (256 KB)
// rank   @ 0x080000   (4 MB)
// csr    @ 0x480000   (8 MB, N*64 ushort, zeroed; holes gather row 0, masked)
// xh     @ 0xC80000   (8 MB = lo half 4 MB | hi half 4 MB)  fp16 x
// tA     @ 0x1480000  (8 MB = lo | hi)  state t = dinv .* p, fp16
// tB     @ 0x1C80000  (8 MB = lo | hi)
// Feature-half tables: row = 32 fp16 = 64 B; half h covers features h*32..h*32+31.
// The ENTIRE 9-hop chain runs on half 0, then half 1 (features are independent
// through A_hat propagation) -> each phase's gather table is 4 MB and fits a
// per-XCD L2 completely. This is the launch-granular address restriction that
// round-4's per-wave src-half phases could not provide (waves drifted, both
// halves live device-wide -> no residency gain).

// Round-0 split build (measured faster than fused: ~65-70 vs 81 us).
__global__ void count_deg(const int* __restrict__ dst, int* __restrict__ counts,
                          int* __restrict__ rank) {
    int e = blockIdx.x * blockDim.x + threadIdx.x;
    if (e < N_EDGES) rank[e] = atomicAdd(&counts[dst[e]], 1);
}

__global__ void compute_dinv(const int* __restrict__ counts, float* __restrict__ dinv) {
    int v = blockIdx.x * blockDim.x + threadIdx.x;
    if (v < N_NODES) dinv[v] = rsqrtf((float)(counts[v] + 1));  // +1 self-loop
}

__global__ void scatter_src(const int* __restrict__ src, const int* __restrict__ dst,
                            const int* __restrict__ rank,
                            unsigned short* __restrict__ csr) {
    int e = blockIdx.x * blockDim.x + threadIdx.x;
    if (e >= N_EDGES) return;
    int r = rank[e];
    if (r < BUCKET) csr[dst[e] * BUCKET + r] = (unsigned short)src[e];
}

// t0 = fp16(dinv .* x), xh = fp16(x), both split into feature-half tables.
__global__ void cvt_x(const float* __restrict__ x, const float* __restrict__ dinv,
                      __half* __restrict__ t0, __half* __restrict__ xh) {
    int i = blockIdx.x * blockDim.x + threadIdx.x;  // i < N*16
    int v = i >> 4;
    int o = i & 15;   // feature quad 0..15
    float dv = dinv[v];
    float4 val = ((const float4*)x)[i];
    __half2 xl = __floats2half2_rn(val.x, val.y);
    __half2 xh2 = __floats2half2_rn(val.z, val.w);
    ull ox = ((ull)(*(const unsigned*)&xh2) << 32) | (*(const unsigned*)&xl);
    __half2 tl = __floats2half2_rn(dv * val.x, dv * val.y);
    __half2 th = __floats2half2_rn(dv * val.z, dv * val.w);
    ull ot = ((ull)(*(const unsigned*)&th) << 32) | (*(const unsigned*)&tl);
    // dest: half = o>>3 (feats 0-31 vs 32-63); row granule = o&7 (8 B each)
    int idx = (o >> 3) * (HALF_ELEMS / 4) + v * 8 + (o & 7);
    ((ull*)xh)[idx] = ox;
    ((ull*)t0)[idx] = ot;
}

// Horner hop on ONE feature-half:
//   p_out[d] = sc*dinv[d]*(sum_e t[src_e] + t[d]) + temp[k]*x[d]
//   t_out[d] = dinv[d]*p_out[d]  (k<9; k==9 writes p fp32)
// FOUR nodes per wave (round-0 geometry). lane = 8q+f: q = slot 0..7 in a
// granule-of-8, f = feature oct (8 B; 8 lanes = one 64 B half-row). Per iter:
// 32 slots/node via 4 granules -> 16 independent 512 B gather instructions per
// dependence-free block (the proven round-0 in-flight shape; 16 > 8 > 2 ranked
// exactly with measured speed, rounds 0-2). iters = ceil(max4/32) = 1 almost
// always -> same ~32 scanned slots/node as round 0. Holes gather row 0
// (L1-hot) and are cndmask-zeroed. Gather table = 4 MB -> per-XCD L2-resident.
__global__ void __launch_bounds__(256) hop_kernel(
        const __half* __restrict__ tab, const __half* __restrict__ xh,
        __half* __restrict__ tab_out, float* __restrict__ out_f32,
        const float* __restrict__ temp, const int* __restrict__ counts,
        const unsigned short* __restrict__ csr, const float* __restrict__ dinv,
        int k) {
    int gtid = blockIdx.x * blockDim.x + threadIdx.x;
    int wave = __builtin_amdgcn_readfirstlane(gtid >> 6);
    int lane = gtid & 63;
    int q = lane >> 3;   // edge slot within granule of 8
    int f = lane & 7;    // feature oct (8 B)

    int v0 = wave * 4;
    float tk = temp[k];
    float sc = (k == 1) ? temp[0] : 1.0f;

    int4 cv = *(const int4*)(counts + v0);     // wave-uniform -> s_load_dwordx4
    int cnt[4];
    cnt[0] = min(cv.x, BUCKET); cnt[1] = min(cv.y, BUCKET);
    cnt[2] = min(cv.z, BUCKET); cnt[3] = min(cv.w, BUCKET);
    float4 dvv = *(const float4*)(dinv + v0);
    float dv[4] = {dvv.x, dvv.y, dvv.z, dvv.w};

    int maxc = max(max(cnt[0], cnt[1]), max(cnt[2], cnt[3]));
    int iters = (maxc + 31) >> 5;   // 32 slots per node per iteration (~always 1)

    const ull* t2 = (const ull*)tab;   // 8 B granule; half-row = 8 granules = 64 B
    float a0[4] = {0.f, 0.f, 0.f, 0.f};
    float a1[4] = {0.f, 0.f, 0.f, 0.f};
    float a2[4] = {0.f, 0.f, 0.f, 0.f};
    float a3[4] = {0.f, 0.f, 0.f, 0.f};

    for (int r = 0; r < iters; ++r) {
        int e0 = r * 32;
        #pragma unroll
        for (int j = 0; j < 4; ++j) {
            // 32 ushort srcs = 64 B, wave-uniform -> four scalar dwordx4 loads
            const int4* bp = (const int4*)(csr + (v0 + j) * BUCKET + e0);
            int4 sg0 = bp[0];   // slots  0..7
            int4 sg1 = bp[1];   // slots  8..15
            int4 sg2 = bp[2];   // slots 16..23
            int4 sg3 = bp[3];   // slots 24..31
            #pragma unroll
            for (int g = 0; g < 4; ++g) {
                int4 sg = (g == 0) ? sg0 : (g == 1) ? sg1 : (g == 2) ? sg2 : sg3;
                int word = (q & 4) ? ((q & 2) ? sg.w : sg.z)
                                   : ((q & 2) ? sg.y : sg.x);
                int s = (word >> ((q & 1) * 16)) & 0xffff;   // slot e0+8g+q's src
                ull row = t2[s * 8 + f];                     // 64 B half-row gather
                row = ((e0 + 8 * g + q) < cnt[j]) ? row : 0ull;  // mask holes
                unsigned rl = (unsigned)row, rh = (unsigned)(row >> 32);
                float2 lo = __half22float2(*(const __half2*)&rl);
                float2 hi = __half22float2(*(const __half2*)&rh);
                a0[j] += lo.x; a1[j] += lo.y; a2[j] += hi.x; a3[j] += hi.y;
            }
        }
    }

    // reduce across the 8 q-groups (lane bits 3,4,5)
    #pragma unroll
    for (int j = 0; j < 4; ++j) {
        a0[j] += __shfl_xor(a0[j], 8); a0[j] += __shfl_xor(a0[j], 16); a0[j] += __shfl_xor(a0[j], 32);
        a1[j] += __shfl_xor(a1[j], 8); a1[j] += __shfl_xor(a1[j], 16); a1[j] += __shfl_xor(a1[j], 32);
        a2[j] += __shfl_xor(a2[j], 8); a2[j] += __shfl_xor(a2[j], 16); a2[j] += __shfl_xor(a2[j], 32);
        a3[j] += __shfl_xor(a3[j], 8); a3[j] += __shfl_xor(a3[j], 16); a3[j] += __shfl_xor(a3[j], 32);
    }

    #pragma unroll
    for (int j = 0; j < 4; ++j) {
        int v = v0 + j;
        ull sx = ((const ull*)xh)[v * 8 + f];   // additive x term (fp16, broadcast)
        ull st = t2[v * 8 + f];                 // self term t[d]
        unsigned sxl = (unsigned)sx, sxh2 = (unsigned)(sx >> 32);
        unsigned stl = (unsigned)st, sth = (unsigned)(st >> 32);
        float2 xlo = __half22float2(*(const __half2*)&sxl);
        float2 xhi = __half22float2(*(const __half2*)&sxh2);
        float2 slo = __half22float2(*(const __half2*)&stl);
        float2 shi = __half22float2(*(const __half2*)&sth);
        float m = sc * dv[j];
        float r0 = m * (a0[j] + slo.x) + tk * xlo.x;
        float r1 = m * (a1[j] + slo.y) + tk * xlo.y;
        float r2 = m * (a2[j] + shi.x) + tk * xhi.x;
        float r3 = m * (a3[j] + shi.y) + tk * xhi.y;
        if (q == 0) {   // lanes 0..7 -> contiguous 64 B (fp16) / 128 B (fp32)
            if (k == 9) {
                vfloat4 o = {r0, r1, r2, r3};
                ((vfloat4*)out_f32)[v * 16 + f] = o;   // out_f32 pre-offset by phase
            } else {
                float d2 = dv[j];
                __half2 plo = __floats2half2_rn(d2 * r0, d2 * r1);
                __half2 phi = __floats2half2_rn(d2 * r2, d2 * r3);
                ull o = ((ull)(*(const unsigned*)&phi) << 32)
                      | (*(const unsigned*)&plo);
                ((ull*)tab_out)[v * 8 + f] = o;
            }
        }
    }
}

extern "C" void kernel_launch(void* const* d_in, const int* in_sizes, int n_in,
                              void* d_out, int out_size, void* d_ws, size_t ws_size,
                              hipStream_t stream) {
    const float* x    = (const float*)d_in[0];
    const float* temp = (const float*)d_in[1];
    const int*   ei   = (const int*)d_in[2];
    const int* src = ei;             // edge_index[0]
    const int* dst = ei + N_EDGES;   // edge_index[1]
    float* out = (float*)d_out;

    char* ws = (char*)d_ws;
    int*            counts = (int*)            (ws + 0x000000);
    float*          dinv   = (float*)          (ws + 0x040000);
    int*            rank   = (int*)            (ws + 0x080000);
    unsigned short* csr    = (unsigned short*) (ws + 0x480000);   // 8 MB
    __half*         xh     = (__half*)         (ws + 0xC80000);
    __half*         tA     = (__half*)         (ws + 0x1480000);
    __half*         tB     = (__half*)         (ws + 0x1C80000);

    (void)hipMemsetAsync(counts, 0, N_NODES * sizeof(int), stream);
    (void)hipMemsetAsync(csr, 0, N_NODES * BUCKET * sizeof(unsigned short), stream);

    count_deg<<<N_EDGES / 256, 256, 0, stream>>>(dst, counts, rank);
    compute_dinv<<<N_NODES / 256, 256, 0, stream>>>(counts, dinv);
    scatter_src<<<N_EDGES / 256, 256, 0, stream>>>(src, dst, rank, csr);
    cvt_x<<<(N_NODES * 16) / 256, 256, 0, stream>>>(x, dinv, tA, xh);

    // Horner per feature-half: p = temp[0]*x; for k=1..9: p = A_hat*p + temp[k]*x.
    // Full 9-hop chain on half 0 (feats 0-31), then half 1 -> gather table is a
    // 4 MB half-table, per-XCD-L2-resident for the whole phase. One transition.
    const int hop_blocks = (N_NODES / 4) * 64 / 256;  // 4 nodes per wave
    for (int ph = 0; ph < 2; ++ph) {
        const __half* xh_ph = xh + ph * HALF_ELEMS;
        float* out_ph = out + ph * 32;                 // feature offset in out rows
        const __half* gin = tA + ph * HALF_ELEMS;
        for (int k = 1; k <= 9; ++k) {
            __half* gout = ((k & 1) ? tB : tA) + ph * HALF_ELEMS;
            hop_kernel<<<hop_blocks, 256, 0, stream>>>(gin, xh_ph, gout, out_ph,
                                                       temp, counts, csr, dinv, k);
            gin = gout;
        }
    }
}

// Round 7
// 358.413 us; speedup vs baseline: 1.4027x; 1.4027x over previous
//
#include <hip/hip_runtime.h>
#include <hip/hip_fp16.h>

#define N_NODES 65536
#define N_EDGES 1048576
#define BUCKET  64   // padded CSR slots per node (deg ~ Poisson(16); P(>64) ~ 1e-18)

typedef float vfloat4 __attribute__((ext_vector_type(4)));
typedef unsigned long long ull;

// ---------------- workspace layout (bytes) ----------------
// counts @ 0x000000   (256 KB)
// dinv   @ 0x040000   (256 KB)
// rank   @ 0x080000   (4 MB)
// csr    @ 0x480000   (8 MB, N*64 ushort, zeroed; holes gather row 0, masked)
// xh     @ 0xC80000   (8 MB)  fp16 x (additive Horner term)
// tA     @ 0x1480000  (8 MB)  state t = dinv .* p, fp16
// tB     @ 0x1C80000  (8 MB)  -- total 36.5 MB
//
// ROUND-0 RESTORATION. Six structural variants (rounds 1-6: MLP width 2/8/32,
// node-per-wave, src-half phases, feature-half chains) all measured >= this.
// Floor model: every phase is outstanding-miss x latency bound (~13 memory
// requests/ns device-wide): hops = 1.05M line-gathers/hop ~30us x9; build =
// 1M atomic returns ~70us; streams ~20us. Sum ~360us = measured.

__global__ void count_deg(const int* __restrict__ dst, int* __restrict__ counts,
                          int* __restrict__ rank) {
    int e = blockIdx.x * blockDim.x + threadIdx.x;
    if (e < N_EDGES) rank[e] = atomicAdd(&counts[dst[e]], 1);
}

__global__ void scatter_src(const int* __restrict__ src, const int* __restrict__ dst,
                            const int* __restrict__ rank,
                            unsigned short* __restrict__ csr) {
    int e = blockIdx.x * blockDim.x + threadIdx.x;
    if (e >= N_EDGES) return;
    int r = rank[e];
    if (r < BUCKET) csr[dst[e] * BUCKET + r] = (unsigned short)src[e];
}

// t0 = fp16(dinv .* x) (gather state), xh = fp16(x) (additive term).
// dinv computed inline from counts (one kernel launch saved) and written
// once per node by the first feature-quad lane.
__global__ void cvt_x(const float* __restrict__ x, const int* __restrict__ counts,
                      float* __restrict__ dinv,
                      __half* __restrict__ t0, __half* __restrict__ xh) {
    int i = blockIdx.x * blockDim.x + threadIdx.x;  // i < N*16
    int v = i >> 4;
    float dv = rsqrtf((float)(counts[v] + 1));      // +1 self-loop
    if ((i & 15) == 0) dinv[v] = dv;
    float4 val = ((const float4*)x)[i];
    __half2 xl = __floats2half2_rn(val.x, val.y);
    __half2 xh2 = __floats2half2_rn(val.z, val.w);
    ull ox = ((ull)(*(const unsigned*)&xh2) << 32) | (*(const unsigned*)&xl);
    __half2 tl = __floats2half2_rn(dv * val.x, dv * val.y);
    __half2 th = __floats2half2_rn(dv * val.z, dv * val.w);
    ull ot = ((ull)(*(const unsigned*)&th) << 32) | (*(const unsigned*)&tl);
    ((ull*)xh)[i] = ox;
    ((ull*)t0)[i] = ot;
}

// Horner hop, dinv folded:  p_out[d] = sc*dinv[d]*(sum_e t[src_e] + t[d]) + temp[k]*x[d]
//                           t_out[d] = dinv[d]*p_out[d]  (k<9; k==9 writes p fp32)
// FOUR nodes per wave (v0..v0+3 wave-uniform -> CSR/meta on the scalar pipe).
// lane = 16q+f: q = edge slot 0..3 per granule-of-4, f = feature quad (8 B;
// 16 lanes = 128 B row). 16 edges per node per iter via 4 granules -> 16
// independent row-gathers in flight per wave (measured optimum: 16 > 8 > 2,
// and 32 loses to VGPR pressure). ushort CSR: two scalar dwordx4 loads cover
// 16 slots. Holes gather row 0 (L1-hot) and are zero-masked.
__global__ void __launch_bounds__(256) hop_kernel(
        const __half* __restrict__ tab, const __half* __restrict__ xh,
        __half* __restrict__ tab_out, float* __restrict__ out_f32,
        const float* __restrict__ temp, const int* __restrict__ counts,
        const unsigned short* __restrict__ csr, const float* __restrict__ dinv,
        int k) {
    int gtid = blockIdx.x * blockDim.x + threadIdx.x;
    int wave = __builtin_amdgcn_readfirstlane(gtid >> 6);
    int lane = gtid & 63;
    int q = lane >> 4;   // edge slot within granule of 4
    int f = lane & 15;   // feature quad (8 B)

    int v0 = wave * 4;
    float tk = temp[k];
    float sc = (k == 1) ? temp[0] : 1.0f;

    int4 cv = *(const int4*)(counts + v0);     // wave-uniform -> s_load_dwordx4
    int cnt[4] = {cv.x, cv.y, cv.z, cv.w};
    float4 dvv = *(const float4*)(dinv + v0);
    float dv[4] = {dvv.x, dvv.y, dvv.z, dvv.w};

    int maxc = max(max(cnt[0], cnt[1]), max(cnt[2], cnt[3]));
    int iters = (maxc + 15) >> 4;   // 16 edges per node per iteration

    const ull* t2 = (const ull*)tab;   // 8 B granule; row = 16 granules = 128 B
    float a0[4] = {0.f, 0.f, 0.f, 0.f};
    float a1[4] = {0.f, 0.f, 0.f, 0.f};
    float a2[4] = {0.f, 0.f, 0.f, 0.f};
    float a3[4] = {0.f, 0.f, 0.f, 0.f};

    for (int r = 0; r < iters; ++r) {
        int e0 = r * 16;
        #pragma unroll
        for (int j = 0; j < 4; ++j) {
            // 16 ushort srcs = 32 B, wave-uniform -> two scalar dwordx4 loads
            const int4* bp = (const int4*)(csr + (v0 + j) * BUCKET + e0);
            int4 sgA = bp[0];   // slots 0..7
            int4 sgB = bp[1];   // slots 8..15
            #pragma unroll
            for (int g = 0; g < 4; ++g) {
                int4 sg = (g & 2) ? sgB : sgA;
                int word = (g & 1) ? ((q & 2) ? sg.w : sg.z)
                                   : ((q & 2) ? sg.y : sg.x);
                int s = (word >> ((q & 1) * 16)) & 0xffff;   // slot 4g+q's src
                ull row = t2[s * 16 + f];
                row = ((e0 + 4 * g + q) < cnt[j]) ? row : 0ull;  // mask holes
                unsigned rl = (unsigned)row, rh = (unsigned)(row >> 32);
                float2 lo = __half22float2(*(const __half2*)&rl);
                float2 hi = __half22float2(*(const __half2*)&rh);
                a0[j] += lo.x; a1[j] += lo.y; a2[j] += hi.x; a3[j] += hi.y;
            }
        }
    }

    #pragma unroll
    for (int j = 0; j < 4; ++j) {
        a0[j] += __shfl_xor(a0[j], 16); a0[j] += __shfl_xor(a0[j], 32);
        a1[j] += __shfl_xor(a1[j], 16); a1[j] += __shfl_xor(a1[j], 32);
        a2[j] += __shfl_xor(a2[j], 16); a2[j] += __shfl_xor(a2[j], 32);
        a3[j] += __shfl_xor(a3[j], 16); a3[j] += __shfl_xor(a3[j], 32);
    }

    #pragma unroll
    for (int j = 0; j < 4; ++j) {
        int v = v0 + j;
        ull sx = ((const ull*)xh)[v * 16 + f];   // additive x term (fp16)
        ull st = t2[v * 16 + f];                 // self term t[d]
        unsigned sxl = (unsigned)sx, sxh2 = (unsigned)(sx >> 32);
        unsigned stl = (unsigned)st, sth = (unsigned)(st >> 32);
        float2 xlo = __half22float2(*(const __half2*)&sxl);
        float2 xhi = __half22float2(*(const __half2*)&sxh2);
        float2 slo = __half22float2(*(const __half2*)&stl);
        float2 shi = __half22float2(*(const __half2*)&sth);
        float m = sc * dv[j];
        float r0 = m * (a0[j] + slo.x) + tk * xlo.x;
        float r1 = m * (a1[j] + slo.y) + tk * xlo.y;
        float r2 = m * (a2[j] + shi.x) + tk * xhi.x;
        float r3 = m * (a3[j] + shi.y) + tk * xhi.y;
        if (q == 0) {
            if (k == 9) {
                vfloat4 o = {r0, r1, r2, r3};
                ((vfloat4*)out_f32)[v * 16 + f] = o;
            } else {
                float d2 = dv[j];
                __half2 plo = __floats2half2_rn(d2 * r0, d2 * r1);
                __half2 phi = __floats2half2_rn(d2 * r2, d2 * r3);
                ull o = ((ull)(*(const unsigned*)&phi) << 32)
                      | (*(const unsigned*)&plo);
                ((ull*)tab_out)[v * 16 + f] = o;
            }
        }
    }
}

extern "C" void kernel_launch(void* const* d_in, const int* in_sizes, int n_in,
                              void* d_out, int out_size, void* d_ws, size_t ws_size,
                              hipStream_t stream) {
    const float* x    = (const float*)d_in[0];
    const float* temp = (const float*)d_in[1];
    const int*   ei   = (const int*)d_in[2];
    const int* src = ei;             // edge_index[0]
    const int* dst = ei + N_EDGES;   // edge_index[1]
    float* out = (float*)d_out;

    char* ws = (char*)d_ws;
    int*            counts = (int*)            (ws + 0x000000);
    float*          dinv   = (float*)          (ws + 0x040000);
    int*            rank   = (int*)            (ws + 0x080000);
    unsigned short* csr    = (unsigned short*) (ws + 0x480000);   // 8 MB
    __half*         xh     = (__half*)         (ws + 0xC80000);
    __half*         tA     = (__half*)         (ws + 0x1480000);
    __half*         tB     = (__half*)         (ws + 0x1C80000);

    (void)hipMemsetAsync(counts, 0, N_NODES * sizeof(int), stream);
    (void)hipMemsetAsync(csr, 0, N_NODES * BUCKET * sizeof(unsigned short), stream);

    count_deg<<<N_EDGES / 256, 256, 0, stream>>>(dst, counts, rank);
    scatter_src<<<N_EDGES / 256, 256, 0, stream>>>(src, dst, rank, csr);
    cvt_x<<<(N_NODES * 16) / 256, 256, 0, stream>>>(x, counts, dinv, tA, xh);

    // Horner: p = temp[0]*x; for k=1..9: p = A_hat*p + temp[k]*x (scale fused in hop1)
    // Table invariant t_k = dinv .* p_k; ping-pong tA -> tB -> tA ...
    const int hop_blocks = (N_NODES / 4) * 64 / 256;  // 4 nodes per wave
    const __half* gin = tA;
    for (int k = 1; k <= 9; ++k) {
        __half* gout = (k & 1) ? tB : tA;
        hop_kernel<<<hop_blocks, 256, 0, stream>>>(gin, xh, gout, out, temp,
                                                   counts, csr, dinv, k);
        gin = gout;
    }
}